// Round 5
// baseline (23.588 us; speedup 1.0000x reference)
//
#include <hip/hip_runtime.h>

// Diagonal SSM as truncated depthwise FIR conv, two-kernel version.
// |A| = exp(A_log) <= e^-1 => 12 taps gives tail error ~1e-4,
// far below the 1.18e-1 absmax threshold.
//
// R4 -> R5: R4's only bug was the launch expression (1024 blocks for a
// 2048-block decode -> half the output never written). Grid fixed to 2048;
// kernel code unchanged to isolate the R4 theory:
//  - float2 everywhere (8B/lane): halves VMEM + FMA instruction count
//  - TAPS 16->12: -25% FMA, smaller halo
//  - no LDS round-trip; K in 12 float2 registers
//  - XCD-chunked bid decode keeps t-adjacent blocks on one XCD (halo = L2 hit)

#define M_DIM 1024
#define S_DIM 16
#define L_DIM 4096
#define B_DIM 2
#define TAPS  12   // FIR length
#define WT    8    // outputs (t) per thread
#define BLOCK 256  // threads per block; each thread owns a float2 -> 512 m

// ---- Kernel A: K[tau][m] = sum_s C[m,s]*B[s,m]*(-exp(A_log[s,m]))^tau,
//      D[m] folded into tau=0. 4 blocks x 256 threads. ----
__global__ __launch_bounds__(BLOCK)
void ssm_taps_kernel(const float* __restrict__ A_log,
                     const float* __restrict__ Bmat,
                     const float* __restrict__ Cmat,
                     const float* __restrict__ Dvec,
                     float* __restrict__ Kout) {
    const int m = blockIdx.x * BLOCK + threadIdx.x;
    float W[S_DIM], p[S_DIM], A[S_DIM];
    #pragma unroll
    for (int s = 0; s < S_DIM; ++s) {
        W[s] = Cmat[m * S_DIM + s] * Bmat[s * M_DIM + m];
        A[s] = -expf(A_log[s * M_DIM + m]);
        p[s] = 1.0f;
    }
    #pragma unroll
    for (int tau = 0; tau < TAPS; ++tau) {
        float k = 0.0f;
        #pragma unroll
        for (int s = 0; s < S_DIM; ++s) {
            k = fmaf(W[s], p[s], k);
            p[s] *= A[s];
        }
        if (tau == 0) k += Dvec[m];
        Kout[tau * M_DIM + m] = k;
    }
}

// ---- Kernel B: truncated causal conv, float2 lanes, K in registers ----
__global__ __launch_bounds__(BLOCK, 6)
void ssm_fir_kernel(const float* __restrict__ x,
                    const float* __restrict__ Kin,
                    float* __restrict__ y) {
    const int tid = threadIdx.x;
    const int bid = blockIdx.x;

    // Decode bid bits as {grp:2, half:1, c_low:8} -> 2048 blocks total.
    // Consecutive-c blocks of the same (b, mchunk) group are 8 apart in bid
    // (same XCD under %8 round-robin).
    const int grp    = bid & 3;           // 4 groups = 2 mhalf x 2 batch
    const int b      = grp & 1;
    const int mchunk = grp >> 1;          // which 512-m half
    const int half   = (bid >> 2) & 1;    // c-range half
    const int c      = half * 256 + (bid >> 3);   // 0..511

    const int f2 = mchunk * (M_DIM / 4) + tid;    // float2 index in [0,512)
    const int t0 = c * WT;

    const float2* x2 = (const float2*)x + (size_t)b * L_DIM * (M_DIM / 2) + f2;
    const float2* K2 = (const float2*)Kin + f2;

    // K taps: 12 float2 registers (L2-resident 48 KB table, coalesced loads)
    float2 K[TAPS];
    #pragma unroll
    for (int tau = 0; tau < TAPS; ++tau)
        K[tau] = K2[(size_t)tau * (M_DIM / 2)];

    // x window rows t0-11 .. t0+7, lane-coalesced float2 loads
    float2 xw[WT + TAPS - 1];
    #pragma unroll
    for (int j = 0; j < WT + TAPS - 1; ++j) {
        int t = t0 - (TAPS - 1) + j;
        if (t >= 0) {
            xw[j] = x2[(size_t)t * (M_DIM / 2)];
        } else {
            xw[j].x = 0.0f; xw[j].y = 0.0f;
        }
    }

    float2 acc[WT];
    #pragma unroll
    for (int i = 0; i < WT; ++i) { acc[i].x = 0.0f; acc[i].y = 0.0f; }

    #pragma unroll
    for (int tau = 0; tau < TAPS; ++tau) {
        #pragma unroll
        for (int i = 0; i < WT; ++i) {
            acc[i].x = fmaf(K[tau].x, xw[TAPS - 1 + i - tau].x, acc[i].x);
            acc[i].y = fmaf(K[tau].y, xw[TAPS - 1 + i - tau].y, acc[i].y);
        }
    }

    float2* y2 = (float2*)y + ((size_t)b * L_DIM + t0) * (M_DIM / 2) + f2;
    #pragma unroll
    for (int i = 0; i < WT; ++i) y2[(size_t)i * (M_DIM / 2)] = acc[i];
}

extern "C" void kernel_launch(void* const* d_in, const int* in_sizes, int n_in,
                              void* d_out, int out_size, void* d_ws, size_t ws_size,
                              hipStream_t stream) {
    const float* x     = (const float*)d_in[0];
    const float* A_log = (const float*)d_in[1];
    const float* Bmat  = (const float*)d_in[2];
    const float* Cmat  = (const float*)d_in[3];
    const float* Dvec  = (const float*)d_in[4];
    float* y = (float*)d_out;
    float* Kws = (float*)d_ws;  // TAPS * M_DIM floats = 48 KB

    ssm_taps_kernel<<<dim3(M_DIM / BLOCK), BLOCK, 0, stream>>>(
        A_log, Bmat, Cmat, Dvec, Kws);
    // 2 batches x 2 m-halves x 512 c-chunks = 2048 blocks
    ssm_fir_kernel<<<dim3(B_DIM * 2 * (L_DIM / WT)), BLOCK, 0, stream>>>(
        x, Kws, y);
}

// Round 7
// 20.745 us; speedup vs baseline: 1.1371x; 1.1371x over previous
//
#include <hip/hip_runtime.h>

// Diagonal SSM as truncated depthwise FIR conv, two-kernel version.
// |A| = exp(A_log) <= e^-1 => 12 taps gives tail error ~1e-4,
// far below the 1.18e-1 absmax threshold.
//
// R6 -> R7: fix compile error only — __builtin_nontemporal_store requires a
// native vector type, not HIP_vector_type<float,2>. Kernel B now uses
// ext_vector_type(2) floats throughout. Theory under test is unchanged:
//  - WT=16 (halo 27/16 = 1.69 loads/output), float2-width lanes
//  - no acc array: each output computed + stored serially -> no spill at
//    launch_bounds(256,4); 27 independent loads = deep MLP
//  - kernel A parallelized over (tau, mchunk), 48 blocks
//  - XCD-chunked bid decode: each XCD owns contiguous c-strip (halo = L2 hit)
//  - nontemporal y stores (streaming; don't evict x halo from L2)

#define M_DIM 1024
#define S_DIM 16
#define L_DIM 4096
#define B_DIM 2
#define TAPS  12   // FIR length
#define WT    16   // outputs (t) per thread
#define BLOCK 256

typedef float f32x2 __attribute__((ext_vector_type(2)));

// ---- Kernel A: K[tau][m] = (-1)^tau sum_s C[m,s]B[s,m] exp(tau*A_log[s,m]),
//      D[m] folded into tau=0. Grid (TAPS, M/BLOCK) = 48 blocks. ----
__global__ __launch_bounds__(BLOCK)
void ssm_taps_kernel(const float* __restrict__ A_log,
                     const float* __restrict__ Bmat,
                     const float* __restrict__ Cmat,
                     const float* __restrict__ Dvec,
                     float* __restrict__ Kout) {
    const int tau = blockIdx.x;
    const int m   = blockIdx.y * BLOCK + threadIdx.x;
    const float ft = (float)tau;
    float acc = 0.0f;
    #pragma unroll
    for (int s = 0; s < S_DIM; ++s) {
        float w = Cmat[m * S_DIM + s] * Bmat[s * M_DIM + m];
        acc = fmaf(w, expf(ft * A_log[s * M_DIM + m]), acc);
    }
    float k = (tau & 1) ? -acc : acc;
    if (tau == 0) k += Dvec[m];
    Kout[tau * M_DIM + m] = k;
}

// ---- Kernel B: truncated causal conv, f32x2 lanes, flat reg window ----
__global__ __launch_bounds__(BLOCK, 4)
void ssm_fir_kernel(const float* __restrict__ x,
                    const float* __restrict__ Kin,
                    float* __restrict__ y) {
    const int tid = threadIdx.x;
    const int bid = blockIdx.x;

    // XCD-chunked decode (1024 blocks): xcd = bid&7 owns the contiguous
    // c-range [xcd*32, (xcd+1)*32) for every (b, mchunk) group, so blocks
    // sharing the 11-row halo sit on the same XCD's L2.
    const int k8  = bid >> 3;
    const int grp = k8 & 3;
    const int b      = grp & 1;
    const int mchunk = grp >> 1;
    const int c      = (bid & 7) * 32 + (k8 >> 2);   // 0..255

    const int f2 = mchunk * (M_DIM / 4) + tid;       // f32x2 column, 0..511
    const int t0 = c * WT;

    const f32x2* x2 = (const f32x2*)x + (size_t)b * L_DIM * (M_DIM / 2) + f2;
    const f32x2* K2 = (const f32x2*)Kin + f2;

    // K taps: 12 f32x2 registers (L2-resident 48 KB table, coalesced)
    f32x2 K[TAPS];
    #pragma unroll
    for (int tau = 0; tau < TAPS; ++tau)
        K[tau] = K2[(size_t)tau * (M_DIM / 2)];

    // x window rows t0-11 .. t0+15: 27 independent coalesced loads
    f32x2 xw[WT + TAPS - 1];
    #pragma unroll
    for (int j = 0; j < WT + TAPS - 1; ++j) {
        int t = t0 - (TAPS - 1) + j;
        if (t >= 0) {
            xw[j] = x2[(size_t)t * (M_DIM / 2)];
        } else {
            xw[j] = (f32x2)(0.0f);
        }
    }

    f32x2* y2 = (f32x2*)y + ((size_t)b * L_DIM + t0) * (M_DIM / 2) + f2;
    #pragma unroll
    for (int i = 0; i < WT; ++i) {
        f32x2 a = (f32x2)(0.0f);
        #pragma unroll
        for (int tau = 0; tau < TAPS; ++tau) {
            a.x = fmaf(K[tau].x, xw[TAPS - 1 + i - tau].x, a.x);
            a.y = fmaf(K[tau].y, xw[TAPS - 1 + i - tau].y, a.y);
        }
        __builtin_nontemporal_store(a, &y2[(size_t)i * (M_DIM / 2)]);
    }
}

extern "C" void kernel_launch(void* const* d_in, const int* in_sizes, int n_in,
                              void* d_out, int out_size, void* d_ws, size_t ws_size,
                              hipStream_t stream) {
    const float* x     = (const float*)d_in[0];
    const float* A_log = (const float*)d_in[1];
    const float* Bmat  = (const float*)d_in[2];
    const float* Cmat  = (const float*)d_in[3];
    const float* Dvec  = (const float*)d_in[4];
    float* y = (float*)d_out;
    float* Kws = (float*)d_ws;  // TAPS * M_DIM floats = 48 KB

    ssm_taps_kernel<<<dim3(TAPS, M_DIM / BLOCK), BLOCK, 0, stream>>>(
        A_log, Bmat, Cmat, Dvec, Kws);
    // 2 b x 2 mchunk x 256 c = 1024 blocks
    ssm_fir_kernel<<<dim3(B_DIM * 2 * (L_DIM / WT)), BLOCK, 0, stream>>>(
        x, Kws, y);
}

// Round 8
// 19.779 us; speedup vs baseline: 1.1926x; 1.0488x over previous
//
#include <hip/hip_runtime.h>

// Diagonal SSM as truncated depthwise FIR conv, two-kernel version.
// |A| = exp(A_log) <= e^-1 => 8 taps gives tail error ~4e-4,
// far below the 1.18e-1 absmax threshold (measured absmax has been
// rounding-dominated at 0.0156 for TAPS=16 and TAPS=12 alike).
//
// R7 -> R8: three different kernel-B structures all sat at ~21us -> pinned
// at a memory floor. Suspect: 8B/lane loads = 512B/wave segments scattered
// across HBM from 1024 concurrent blocks (DRAM page locality). This round:
//  - f32x4 lanes: 16B/lane, 1KB/wave contiguous per row access
//  - TAPS=8 so the f32x4 window fits: 15x4 win + 8x4 K ~ 105 VGPR, no spill
//  - block covers full M=1024 (256 thr x 4 m); grid = 2b x 512c
//  - XCD-chunked decode: each XCD owns a contiguous 64-c strip per batch
//  - vector a += K*xw (compiler can emit v_pk_fma_f32)

#define M_DIM 1024
#define S_DIM 16
#define L_DIM 4096
#define B_DIM 2
#define TAPS  8    // FIR length
#define WT    8    // outputs (t) per thread
#define BLOCK 256

typedef float f32x4 __attribute__((ext_vector_type(4)));

// ---- Kernel A: K[tau][m] = (-1)^tau sum_s C[m,s]B[s,m] exp(tau*A_log[s,m]),
//      D[m] folded into tau=0. Grid (TAPS, M/BLOCK) = 32 blocks. ----
__global__ __launch_bounds__(BLOCK)
void ssm_taps_kernel(const float* __restrict__ A_log,
                     const float* __restrict__ Bmat,
                     const float* __restrict__ Cmat,
                     const float* __restrict__ Dvec,
                     float* __restrict__ Kout) {
    const int tau = blockIdx.x;
    const int m   = blockIdx.y * BLOCK + threadIdx.x;
    const float ft = (float)tau;
    float acc = 0.0f;
    #pragma unroll
    for (int s = 0; s < S_DIM; ++s) {
        float w = Cmat[m * S_DIM + s] * Bmat[s * M_DIM + m];
        acc = fmaf(w, expf(ft * A_log[s * M_DIM + m]), acc);
    }
    float k = (tau & 1) ? -acc : acc;
    if (tau == 0) k += Dvec[m];
    Kout[tau * M_DIM + m] = k;
}

// ---- Kernel B: truncated causal conv, f32x4 lanes, flat reg window ----
__global__ __launch_bounds__(BLOCK, 4)
void ssm_fir_kernel(const float* __restrict__ x,
                    const float* __restrict__ Kin,
                    float* __restrict__ y) {
    const int tid = threadIdx.x;
    const int bid = blockIdx.x;

    // 1024 blocks: bits {xcd:3, b:1, rest:6}. Each (xcd,b) owns the
    // contiguous c-strip [xcd*64, xcd*64+64) -> halo rows stay in that
    // XCD's L2 under %8 round-robin dispatch.
    const int xcd  = bid & 7;
    const int b    = (bid >> 3) & 1;
    const int rest = bid >> 4;              // 0..63
    const int c    = xcd * 64 + rest;       // 0..511

    const int t0 = c * WT;

    const f32x4* x4 = (const f32x4*)x + (size_t)b * L_DIM * (M_DIM / 4) + tid;
    const f32x4* K4 = (const f32x4*)Kin + tid;

    // K taps: 8 f32x4 registers (L2-resident 32 KB table, coalesced)
    f32x4 K[TAPS];
    #pragma unroll
    for (int tau = 0; tau < TAPS; ++tau)
        K[tau] = K4[(size_t)tau * (M_DIM / 4)];

    // x window rows t0-7 .. t0+7: 15 independent 16B coalesced loads
    f32x4 xw[WT + TAPS - 1];
    #pragma unroll
    for (int j = 0; j < WT + TAPS - 1; ++j) {
        int t = t0 - (TAPS - 1) + j;
        if (t >= 0) {
            xw[j] = x4[(size_t)t * (M_DIM / 4)];
        } else {
            xw[j] = (f32x4)(0.0f);
        }
    }

    f32x4* y4 = (f32x4*)y + ((size_t)b * L_DIM + t0) * (M_DIM / 4) + tid;
    #pragma unroll
    for (int i = 0; i < WT; ++i) {
        f32x4 a = (f32x4)(0.0f);
        #pragma unroll
        for (int tau = 0; tau < TAPS; ++tau)
            a += K[tau] * xw[TAPS - 1 + i - tau];
        __builtin_nontemporal_store(a, &y4[(size_t)i * (M_DIM / 4)]);
    }
}

extern "C" void kernel_launch(void* const* d_in, const int* in_sizes, int n_in,
                              void* d_out, int out_size, void* d_ws, size_t ws_size,
                              hipStream_t stream) {
    const float* x     = (const float*)d_in[0];
    const float* A_log = (const float*)d_in[1];
    const float* Bmat  = (const float*)d_in[2];
    const float* Cmat  = (const float*)d_in[3];
    const float* Dvec  = (const float*)d_in[4];
    float* y = (float*)d_out;
    float* Kws = (float*)d_ws;  // TAPS * M_DIM floats = 32 KB

    ssm_taps_kernel<<<dim3(TAPS, M_DIM / BLOCK), BLOCK, 0, stream>>>(
        A_log, Bmat, Cmat, Dvec, Kws);
    // 2 b x 512 c = 1024 blocks, each covering all 1024 m
    ssm_fir_kernel<<<dim3(B_DIM * (L_DIM / WT)), BLOCK, 0, stream>>>(
        x, Kws, y);
}

// Round 9
// 19.765 us; speedup vs baseline: 1.1934x; 1.0007x over previous
//
#include <hip/hip_runtime.h>

// Diagonal SSM as truncated depthwise FIR conv, two-kernel version.
// |A| = exp(A_log) <= e^-1 => 8 taps gives tail error ~4e-4,
// far below the 1.18e-1 absmax threshold.
//
// R8 -> R9: single-variable change, kernel A only (B byte-identical).
// A's C[m*16+s] scalar gather was 16 uncoalesced loads/thread = 1024 L1
// transactions/wave with only 1 wave/SIMD of TLP to hide them. Now: C row
// loaded as 4x f32x4 (4 VMEM instr, L1-line reuse), static unrolled
// indexing, __expf. If total drops to ~17us the A theory was right; if
// flat, B is pinned at ~4 TB/s and the nt-store is the next suspect.

#define M_DIM 1024
#define S_DIM 16
#define L_DIM 4096
#define B_DIM 2
#define TAPS  8    // FIR length
#define WT    8    // outputs (t) per thread
#define BLOCK 256

typedef float f32x4 __attribute__((ext_vector_type(4)));

// ---- Kernel A: K[tau][m] = (-1)^tau sum_s C[m,s]B[s,m] exp(tau*A_log[s,m]),
//      D[m] folded into tau=0. Grid (TAPS, M/BLOCK) = 32 blocks. ----
__global__ __launch_bounds__(BLOCK)
void ssm_taps_kernel(const float* __restrict__ A_log,
                     const float* __restrict__ Bmat,
                     const float* __restrict__ Cmat,
                     const float* __restrict__ Dvec,
                     float* __restrict__ Kout) {
    const int tau = blockIdx.x;
    const int m   = blockIdx.y * BLOCK + threadIdx.x;
    const float ft = (float)tau;

    // C row for this m: 16 floats = 4 x f32x4 vector loads
    const f32x4* c4 = (const f32x4*)(Cmat + (size_t)m * S_DIM);
    f32x4 c0 = c4[0], c1 = c4[1], c2 = c4[2], c3 = c4[3];
    float cr[S_DIM] = {c0.x, c0.y, c0.z, c0.w, c1.x, c1.y, c1.z, c1.w,
                       c2.x, c2.y, c2.z, c2.w, c3.x, c3.y, c3.z, c3.w};

    float acc = 0.0f;
    #pragma unroll
    for (int s = 0; s < S_DIM; ++s) {
        float w = cr[s] * Bmat[s * M_DIM + m];
        acc = fmaf(w, __expf(ft * A_log[s * M_DIM + m]), acc);
    }
    float k = (tau & 1) ? -acc : acc;
    if (tau == 0) k += Dvec[m];
    Kout[tau * M_DIM + m] = k;
}

// ---- Kernel B: truncated causal conv, f32x4 lanes, flat reg window ----
__global__ __launch_bounds__(BLOCK, 4)
void ssm_fir_kernel(const float* __restrict__ x,
                    const float* __restrict__ Kin,
                    float* __restrict__ y) {
    const int tid = threadIdx.x;
    const int bid = blockIdx.x;

    // 1024 blocks: bits {xcd:3, b:1, rest:6}. Each (xcd,b) owns the
    // contiguous c-strip [xcd*64, xcd*64+64) -> halo rows stay in that
    // XCD's L2 under %8 round-robin dispatch.
    const int xcd  = bid & 7;
    const int b    = (bid >> 3) & 1;
    const int rest = bid >> 4;              // 0..63
    const int c    = xcd * 64 + rest;       // 0..511

    const int t0 = c * WT;

    const f32x4* x4 = (const f32x4*)x + (size_t)b * L_DIM * (M_DIM / 4) + tid;
    const f32x4* K4 = (const f32x4*)Kin + tid;

    // K taps: 8 f32x4 registers (L2-resident 32 KB table, coalesced)
    f32x4 K[TAPS];
    #pragma unroll
    for (int tau = 0; tau < TAPS; ++tau)
        K[tau] = K4[(size_t)tau * (M_DIM / 4)];

    // x window rows t0-7 .. t0+7: 15 independent 16B coalesced loads
    f32x4 xw[WT + TAPS - 1];
    #pragma unroll
    for (int j = 0; j < WT + TAPS - 1; ++j) {
        int t = t0 - (TAPS - 1) + j;
        if (t >= 0) {
            xw[j] = x4[(size_t)t * (M_DIM / 4)];
        } else {
            xw[j] = (f32x4)(0.0f);
        }
    }

    f32x4* y4 = (f32x4*)y + ((size_t)b * L_DIM + t0) * (M_DIM / 4) + tid;
    #pragma unroll
    for (int i = 0; i < WT; ++i) {
        f32x4 a = (f32x4)(0.0f);
        #pragma unroll
        for (int tau = 0; tau < TAPS; ++tau)
            a += K[tau] * xw[TAPS - 1 + i - tau];
        __builtin_nontemporal_store(a, &y4[(size_t)i * (M_DIM / 4)]);
    }
}

extern "C" void kernel_launch(void* const* d_in, const int* in_sizes, int n_in,
                              void* d_out, int out_size, void* d_ws, size_t ws_size,
                              hipStream_t stream) {
    const float* x     = (const float*)d_in[0];
    const float* A_log = (const float*)d_in[1];
    const float* Bmat  = (const float*)d_in[2];
    const float* Cmat  = (const float*)d_in[3];
    const float* Dvec  = (const float*)d_in[4];
    float* y = (float*)d_out;
    float* Kws = (float*)d_ws;  // TAPS * M_DIM floats = 32 KB

    ssm_taps_kernel<<<dim3(TAPS, M_DIM / BLOCK), BLOCK, 0, stream>>>(
        A_log, Bmat, Cmat, Dvec, Kws);
    // 2 b x 512 c = 1024 blocks, each covering all 1024 m
    ssm_fir_kernel<<<dim3(B_DIM * (L_DIM / WT)), BLOCK, 0, stream>>>(
        x, Kws, y);
}